// Round 17
// baseline (241.801 us; speedup 1.0000x reference)
//
#include <hip/hip_runtime.h>
#include <hip/hip_bf16.h>

#define NB 8
#define NG 8
#define NT 4096
#define NDIM 1024
#define NGD 128
#define NATT 128
#define NKL 256
#define FSCALE 0.08838834764831845f  // 1/sqrt(128)

typedef __bf16 bf16x8 __attribute__((ext_vector_type(8)));
typedef float f32x4 __attribute__((ext_vector_type(4)));
typedef ushort u16x8 __attribute__((ext_vector_type(8)));
typedef ushort u16x4 __attribute__((ext_vector_type(4)));

#define MFMA(a, b, c) __builtin_amdgcn_mfma_f32_16x16x32_bf16(a, b, c, 0, 0, 0)

__device__ __forceinline__ ushort f2bf(float f) {  // RNE
  union { float f; unsigned u; } v; v.f = f;
  unsigned r = v.u + 0x7FFFu + ((v.u >> 16) & 1u);
  return (ushort)(r >> 16);
}

__device__ __forceinline__ void gload16(const ushort* g, ushort* l) {
  __builtin_amdgcn_global_load_lds(
      (const __attribute__((address_space(1))) unsigned int*)g,
      (__attribute__((address_space(3))) unsigned int*)l, 16, 0, 0);
}

// ---------------------------------------------------------------------------
// K0: weight folding. FROZEN (R12-proven, ~8 us).
// ---------------------------------------------------------------------------
__global__ __launch_bounds__(512) void k0_weights(
    const float* __restrict__ Wq, const float* __restrict__ Wk,
    const float* __restrict__ Wv, const float* __restrict__ Wo,
    ushort* __restrict__ WkQT, ushort* __restrict__ WvoT) {
  const int sel = blockIdx.x;
  const int g = blockIdx.y;
  __shared__ float A2[128 * 136];
  __shared__ float B2[128 * 136];
  const int tid = threadIdx.x;

  if (sel == 0) {
#pragma unroll
    for (int u = 0; u < 8; ++u) {
      const int c = tid + 512 * u;
      const int row = c >> 5, c4 = (c & 31) * 4;
      *(float4*)&A2[row * 136 + c4] =
          *(const float4*)&Wo[(size_t)g * 16384 + row * 128 + c4];
      const float4 v = *(const float4*)&Wv[(size_t)g * 16384 + row * 128 + c4];
      B2[(c4 + 0) * 136 + row] = v.x;
      B2[(c4 + 1) * 136 + row] = v.y;
      B2[(c4 + 2) * 136 + row] = v.z;
      B2[(c4 + 3) * 136 + row] = v.w;
    }
  } else {
#pragma unroll
    for (int u = 0; u < 8; ++u) {
      const int c = tid + 512 * u;
      const int row = c >> 5, c4 = (c & 31) * 4;
      const float4 q = *(const float4*)&Wq[(size_t)g * 16384 + row * 128 + c4];
      A2[(c4 + 0) * 136 + row] = q.x;
      A2[(c4 + 1) * 136 + row] = q.y;
      A2[(c4 + 2) * 136 + row] = q.z;
      A2[(c4 + 3) * 136 + row] = q.w;
      const float4 k = *(const float4*)&Wk[(size_t)g * 16384 + row * 128 + c4];
      B2[(c4 + 0) * 136 + row] = k.x;
      B2[(c4 + 1) * 136 + row] = k.y;
      B2[(c4 + 2) * 136 + row] = k.z;
      B2[(c4 + 3) * 136 + row] = k.w;
    }
  }
  __syncthreads();

  const int mr = tid >> 4;
  const int mc = tid & 15;
  float acc[4][8];
#pragma unroll
  for (int i = 0; i < 4; ++i)
#pragma unroll
    for (int j = 0; j < 8; ++j) acc[i][j] = 0.f;

#pragma unroll 4
  for (int k = 0; k < 128; ++k) {
    const float4 a = *(const float4*)&A2[k * 136 + mr * 4];
    const float4 b0 = *(const float4*)&B2[k * 136 + mc * 8];
    const float4 b1 = *(const float4*)&B2[k * 136 + mc * 8 + 4];
    const float av[4] = {a.x, a.y, a.z, a.w};
    const float bv[8] = {b0.x, b0.y, b0.z, b0.w, b1.x, b1.y, b1.z, b1.w};
#pragma unroll
    for (int i = 0; i < 4; ++i)
#pragma unroll
      for (int j = 0; j < 8; ++j) acc[i][j] += av[i] * bv[j];
  }

  const float sc = sel ? FSCALE : 1.f;
  ushort* dst = (sel ? WkQT : WvoT) + (size_t)g * 16384;
#pragma unroll
  for (int i = 0; i < 4; ++i) {
    u16x8 pk;
#pragma unroll
    for (int j = 0; j < 8; ++j) pk[j] = f2bf(acc[i][j] * sc);
    *(u16x8*)&dst[(size_t)(mr * 4 + i) * 128 + mc * 8] = pk;
  }
}

// ---------------------------------------------------------------------------
// KT_XP: merged transpose kernel (one launch). FROZEN (R12-proven).
// ---------------------------------------------------------------------------
__global__ __launch_bounds__(256) void kt_xp(
    const float* __restrict__ x, const float* __restrict__ Pk,
    const float* __restrict__ Pv, ushort* __restrict__ xT,
    ushort* __restrict__ PkT, ushort* __restrict__ PvT) {
  __shared__ float buf[64 * 132];
  const int bid = blockIdx.x;
  const int tid = threadIdx.x;

  if (bid < 4096) {
    const int t0 = (bid & 63) * 64;
    const int bg = bid >> 6;
    const int b = bg >> 3, g = bg & 7;
#pragma unroll
    for (int u = 0; u < 8; ++u) {
      const int c = tid + 256 * u;
      const int row = c >> 5, c4 = (c & 31) * 4;
      *(float4*)&buf[row * 132 + c4] =
          *(const float4*)&x[((size_t)b * NT + t0 + row) * NDIM + g * 128 + c4];
    }
    __syncthreads();
    const int seg = tid & 7;
    const int d0 = tid >> 3;
#pragma unroll
    for (int u = 0; u < 4; ++u) {
      const int d = d0 + u * 32;
      u16x8 pk;
#pragma unroll
      for (int z = 0; z < 8; ++z) pk[z] = f2bf(buf[(seg * 8 + z) * 132 + d]);
      *(u16x8*)&xT[((size_t)bg * 128 + d) * NT + t0 + seg * 8] = pk;
    }
  } else {
    const int idx = bid - 4096;
    const float* P = (idx >> 10) ? Pv : Pk;
    ushort* PT = (idx >> 10) ? PvT : PkT;
    const int r_ = idx & 1023;
    const int t0 = (r_ & 63) * 64;
    const int klh = (r_ >> 6) & 1;
    const int g = (r_ >> 7) & 7;
#pragma unroll
    for (int u = 0; u < 8; ++u) {
      const int c = tid + 256 * u;
      const int row = c >> 5, c4 = (c & 31) * 4;
      *(float4*)&buf[row * 132 + c4] =
          *(const float4*)&P[((size_t)g * NT + t0 + row) * NKL + klh * 128 + c4];
    }
    __syncthreads();
    const int seg = tid & 7;
    const int k0_ = tid >> 3;
#pragma unroll
    for (int u = 0; u < 4; ++u) {
      const int kl = k0_ + u * 32;
      u16x8 pk;
#pragma unroll
      for (int z = 0; z < 8; ++z) pk[z] = f2bf(buf[(seg * 8 + z) * 132 + kl]);
      *(u16x8*)&PT[((size_t)g * NKL + klh * 128 + kl) * NT + t0 + seg * 8] = pk;
    }
  }
}

// ---------------------------------------------------------------------------
// K1: C1 = P^T@X (128kl x 128d, K=4096, BK=64, global_load_lds dbuf, XOR
// swizzle key row&7), epilogue C2 = C1@W. FROZEN (R12-proven).
// ---------------------------------------------------------------------------
__global__ __launch_bounds__(256, 2) void k1_mfma(
    const ushort* __restrict__ PkT, const ushort* __restrict__ PvT,
    const ushort* __restrict__ xT, const ushort* __restrict__ WkQT,
    const ushort* __restrict__ WvoT, ushort* __restrict__ MQ,
    ushort* __restrict__ vo_redT) {
  const int bid = blockIdx.x;
  const int work = (bid & 7) * 32 + (bid >> 3);  // cluster 8 bg per XCD
  const int bg = work >> 2;
  const int sel = (work >> 1) & 1;
  const int klt = work & 1;
  const int g = bg & 7;
  const ushort* PT = (sel ? PvT : PkT) + ((size_t)g * NKL + klt * 128) * NT;
  const ushort* Xb = xT + (size_t)bg * 128 * NT;

  __shared__ ushort lds[32768];  // 2 bufs x (A 128x64 + B 128x64); C reuse

  const int tid = threadIdx.x;
  const int w = tid >> 6, lane = tid & 63;
  const int l15 = lane & 15, l4 = lane >> 4;
  const int rh = (w & 1) * 64;
  const int ch = (w >> 1) * 64;
  const int srow = lane >> 3, sc = lane & 7;

  f32x4 acc[4][4];
  const f32x4 fz = {0.f, 0.f, 0.f, 0.f};
#pragma unroll
  for (int i = 0; i < 4; ++i)
#pragma unroll
    for (int j = 0; j < 4; ++j) acc[i][j] = fz;

#define K1_STAGE(buf, s)                                                      \
  {                                                                           \
    const int t0_ = (s) * 64;                                                 \
    ushort* Ab_ = &lds[(buf) * 16384];                                        \
    ushort* Bb_ = &lds[(buf) * 16384 + 8192];                                 \
    _Pragma("unroll") for (int u = 0; u < 4; ++u) {                           \
      const int row_ = w * 32 + u * 8 + srow;                                 \
      const size_t off_ = (size_t)row_ * NT + t0_ + ((sc ^ (row_ & 7)) << 3); \
      gload16(PT + off_, Ab_ + (w * 32 + u * 8) * 64);                        \
      gload16(Xb + off_, Bb_ + (w * 32 + u * 8) * 64);                        \
    }                                                                         \
  }

#define K1_COMPUTE(buf)                                                       \
  {                                                                           \
    const ushort* Ab_ = &lds[(buf) * 16384];                                  \
    const ushort* Bb_ = &lds[(buf) * 16384 + 8192];                           \
    _Pragma("unroll") for (int h = 0; h < 2; ++h) {                           \
      bf16x8 af_[4], bf_[4];                                                  \
      _Pragma("unroll") for (int i = 0; i < 4; ++i) {                         \
        const int row_ = rh + i * 16 + l15;                                   \
        af_[i] = *(const bf16x8*)&Ab_[row_ * 64 +                             \
                                      (((h * 4 + l4) ^ (row_ & 7)) << 3)];    \
      }                                                                       \
      _Pragma("unroll") for (int j = 0; j < 4; ++j) {                         \
        const int row_ = ch + j * 16 + l15;                                   \
        bf_[j] = *(const bf16x8*)&Bb_[row_ * 64 +                             \
                                      (((h * 4 + l4) ^ (row_ & 7)) << 3)];    \
      }                                                                       \
      _Pragma("unroll") for (int i = 0; i < 4; ++i)                           \
        _Pragma("unroll") for (int j = 0; j < 4; ++j)                         \
          acc[i][j] = MFMA(af_[i], bf_[j], acc[i][j]);                        \
    }                                                                         \
  }

  K1_STAGE(0, 0);
  __syncthreads();
  int buf = 0;
#pragma unroll 1
  for (int s = 0; s < 64; ++s) {
    if (s + 1 < 64) K1_STAGE(buf ^ 1, s + 1);
    K1_COMPUTE(buf);
    __syncthreads();
    buf ^= 1;
  }

  ushort* C = lds;
#pragma unroll
  for (int i = 0; i < 4; ++i)
#pragma unroll
    for (int j = 0; j < 4; ++j)
#pragma unroll
      for (int r = 0; r < 4; ++r)
        C[(rh + i * 16 + l4 * 4 + r) * 136 + ch + j * 16 + l15] =
            f2bf(acc[i][j][r]);
  __syncthreads();

  const ushort* WT = (sel ? WvoT : WkQT) + (size_t)g * 16384;
  f32x4 o[4][4];
#pragma unroll
  for (int i = 0; i < 4; ++i)
#pragma unroll
    for (int j = 0; j < 4; ++j) o[i][j] = fz;
#pragma unroll
  for (int ks = 0; ks < 4; ++ks) {
    bf16x8 af[4], bfr[4];
#pragma unroll
    for (int i = 0; i < 4; ++i)
      af[i] = *(const bf16x8*)&C[(rh + i * 16 + l15) * 136 + ks * 32 + l4 * 8];
#pragma unroll
    for (int j = 0; j < 4; ++j)
      bfr[j] = *(const bf16x8*)&WT[(size_t)(ch + j * 16 + l15) * 128 + ks * 32 + l4 * 8];
#pragma unroll
    for (int i = 0; i < 4; ++i)
#pragma unroll
      for (int j = 0; j < 4; ++j) o[i][j] = MFMA(af[i], bfr[j], o[i][j]);
  }

  if (sel == 0) {
#pragma unroll
    for (int i = 0; i < 4; ++i)
#pragma unroll
      for (int j = 0; j < 4; ++j)
#pragma unroll
        for (int r = 0; r < 4; ++r)
          MQ[((size_t)bg * NKL + klt * 128 + rh + i * 16 + l4 * 4 + r) * 128 +
             ch + j * 16 + l15] = f2bf(o[i][j][r]);
  } else {
#pragma unroll
    for (int i = 0; i < 4; ++i)
#pragma unroll
      for (int j = 0; j < 4; ++j) {
        u16x4 pk;
#pragma unroll
        for (int r = 0; r < 4; ++r) pk[r] = f2bf(o[i][j][r]);
        *(u16x4*)&vo_redT[((size_t)bg * 128 + ch + j * 16 + l15) * NKL +
                          klt * 128 + rh + i * 16 + l4 * 4] = pk;
      }
  }
}

// ---------------------------------------------------------------------------
// K2: single-barrier-per-step variant of the R14/R16 kernel.
// Changes vs R16 (and ONLY these):
//  - softmax computed vs LOCAL half-max (p = exp(s - m_local) <= 1); m and l
//    exchanged in ONE barrier; global combine done with sc_me/sc_ot <= 1.
//  - PV split into twin accumulators oa0 (kl 0-127) / oa1 (kl 128-255);
//    store emits (sc_h0*oa0 + sc_h1*oa1)*inv. Peak live regs unchanged vs
//    the frozen R4 layout: s[8] is dead (via att LDS) before oa0/oa1 live.
//  - att + redm/reds double-buffered by st&1 (removes the WAR barrier).
// Barriers: 17 -> 9. LDS 139.3 KB (still 1 block/CU). Tripwire: if
// WRITE_SIZE > 200 MB (spill) or absmax > 0.038, revert to R16 = plateau.
// ---------------------------------------------------------------------------
__global__ __launch_bounds__(512, 2) void k2_attn(
    const float* __restrict__ x, const ushort* __restrict__ MQ,
    const ushort* __restrict__ vo_redT, float* __restrict__ out) {
  const int id = blockIdx.x;
  const int bg = id & 63;  // same-bg blocks co-locate on XCD bg%8
  const int tc = id >> 6;  // 0..7, 512 t-rows each
  const int b = bg >> 3, g = bg & 7;

  __shared__ ushort mq[256 * 136];      // 69632 B
  __shared__ ushort att[2][64 * 264];   // 2 x 33792 B (double-buffered)
  __shared__ float redm[2][2][64];
  __shared__ float reds[2][2][64];

  const int tid = threadIdx.x;
  const int w = tid >> 6, lane = tid & 63;
  const int l15 = lane & 15, l4 = lane >> 4;
  const int tw = w >> 1, half = w & 1;
  const f32x4 fz = {0.f, 0.f, 0.f, 0.f};

  {  // stage MQ[bg] -> LDS (padded rows)
    const ushort* src = MQ + (size_t)bg * NKL * 128;
#pragma unroll
    for (int u = 0; u < 8; ++u) {
      const int c = tid + 512 * u;
      const int r = c >> 4, c8 = (c & 15) * 8;
      *(u16x8*)&mq[r * 136 + c8] = *(const u16x8*)&src[r * 128 + c8];
    }
  }

  const float* xb = x + ((size_t)b * NT + tc * 512) * NDIM + g * 128;
  const ushort* vo = vo_redT + ((size_t)bg * 128 + half * 64) * NKL;

  float4 xr[8];  // x fragments for current step (prefetched)
#pragma unroll
  for (int ks = 0; ks < 4; ++ks) {
    const float* p = xb + (size_t)(tw * 16 + l15) * NDIM + ks * 32 + l4 * 8;
    xr[ks * 2] = *(const float4*)p;
    xr[ks * 2 + 1] = *(const float4*)(p + 4);
  }
  __syncthreads();  // mq ready

#pragma unroll 1
  for (int st = 0; st < 8; ++st) {
    const int pb = st & 1;
    ushort* attb = att[pb];
    // convert current x frags to bf16
    bf16x8 a[4];
#pragma unroll
    for (int ks = 0; ks < 4; ++ks) {
      bf16x8 t;
      t[0] = (__bf16)xr[ks * 2].x; t[1] = (__bf16)xr[ks * 2].y;
      t[2] = (__bf16)xr[ks * 2].z; t[3] = (__bf16)xr[ks * 2].w;
      t[4] = (__bf16)xr[ks * 2 + 1].x; t[5] = (__bf16)xr[ks * 2 + 1].y;
      t[6] = (__bf16)xr[ks * 2 + 1].z; t[7] = (__bf16)xr[ks * 2 + 1].w;
      a[ks] = t;
    }
    // prefetch next step's x frags
    if (st + 1 < 8) {
      const float* pn = xb + (size_t)((st + 1) * 64 + tw * 16 + l15) * NDIM;
#pragma unroll
      for (int ks = 0; ks < 4; ++ks) {
        xr[ks * 2] = *(const float4*)(pn + ks * 32 + l4 * 8);
        xr[ks * 2 + 1] = *(const float4*)(pn + ks * 32 + l4 * 8 + 4);
      }
    }
    // S = x @ MQ^T  (wave: t-tile tw, kl-half `half`)
    f32x4 s[8];
#pragma unroll
    for (int n = 0; n < 8; ++n) s[n] = fz;
#pragma unroll
    for (int n = 0; n < 8; ++n) {
      const int row = (half * 8 + n) * 16 + l15;
#pragma unroll
      for (int ks = 0; ks < 4; ++ks) {
        const bf16x8 bv = *(const bf16x8*)&mq[row * 136 + ks * 32 + l4 * 8];
        s[n] = MFMA(a[ks], bv, s[n]);
      }
    }
    // local softmax (vs own-half max only); write unnormalized att
    const int rowbase = tw * 16 + l4 * 4;
    float mx[4], sm[4];
#pragma unroll
    for (int r = 0; r < 4; ++r) {
      float m = s[0][r];
#pragma unroll
      for (int n = 1; n < 8; ++n) m = fmaxf(m, s[n][r]);
#pragma unroll
      for (int off = 1; off < 16; off <<= 1) m = fmaxf(m, __shfl_xor(m, off, 64));
      mx[r] = m;
    }
#pragma unroll
    for (int r = 0; r < 4; ++r) {
      float acc = 0.f;
#pragma unroll
      for (int n = 0; n < 8; ++n) {
        const float p = __expf(s[n][r] - mx[r]);
        acc += p;
        attb[(rowbase + r) * 264 + (half * 8 + n) * 16 + l15] = f2bf(p);
      }
#pragma unroll
      for (int off = 1; off < 16; off <<= 1) acc += __shfl_xor(acc, off, 64);
      sm[r] = acc;
    }
    if (l15 == 0) {
#pragma unroll
      for (int r = 0; r < 4; ++r) {
        redm[pb][half][rowbase + r] = mx[r];
        reds[pb][half][rowbase + r] = sm[r];
      }
    }
    __syncthreads();  // the ONLY barrier per step
    // combine: global max + sum; all scales <= 1
    float sc_me[4], sc_ot[4], inv[4];
#pragma unroll
    for (int r = 0; r < 4; ++r) {
      const float mo = redm[pb][half ^ 1][rowbase + r];
      const float lo = reds[pb][half ^ 1][rowbase + r];
      const float mg = fmaxf(mx[r], mo);
      sc_me[r] = __expf(mx[r] - mg);
      sc_ot[r] = __expf(mo - mg);
      inv[r] = 1.f / (sm[r] * sc_me[r] + lo * sc_ot[r]);
    }
    // PV with twin accumulators: oa0 = kl cols 0-127, oa1 = 128-255
    f32x4 oa0[4], oa1[4];
#pragma unroll
    for (int j = 0; j < 4; ++j) { oa0[j] = fz; oa1[j] = fz; }
#pragma unroll
    for (int ks = 0; ks < 4; ++ks) {
      const bf16x8 av = *(const bf16x8*)&attb[(tw * 16 + l15) * 264 + ks * 32 + l4 * 8];
#pragma unroll
      for (int j = 0; j < 4; ++j) {
        const bf16x8 bv = *(const bf16x8*)&vo[(size_t)(j * 16 + l15) * NKL + ks * 32 + l4 * 8];
        oa0[j] = MFMA(av, bv, oa0[j]);
      }
    }
#pragma unroll
    for (int ks = 4; ks < 8; ++ks) {
      const bf16x8 av = *(const bf16x8*)&attb[(tw * 16 + l15) * 264 + ks * 32 + l4 * 8];
#pragma unroll
      for (int j = 0; j < 4; ++j) {
        const bf16x8 bv = *(const bf16x8*)&vo[(size_t)(j * 16 + l15) * NKL + ks * 32 + l4 * 8];
        oa1[j] = MFMA(av, bv, oa1[j]);
      }
    }
    // store: column-half 0 was written by half-0 wave (its max) and vice versa
    float* ob = out + ((size_t)b * NT + tc * 512 + st * 64 + tw * 16) * NDIM +
                g * 128 + half * 64;
#pragma unroll
    for (int j = 0; j < 4; ++j)
#pragma unroll
      for (int r = 0; r < 4; ++r) {
        const float f0 = half ? sc_ot[r] : sc_me[r];
        const float f1 = half ? sc_me[r] : sc_ot[r];
        ob[(size_t)(l4 * 4 + r) * NDIM + j * 16 + l15] =
            (oa0[j][r] * f0 + oa1[j][r] * f1) * inv[r];
      }
  }
}

// ---------------------------------------------------------------------------
extern "C" void kernel_launch(void* const* d_in, const int* in_sizes, int n_in,
                              void* d_out, int out_size, void* d_ws, size_t ws_size,
                              hipStream_t stream) {
  (void)in_sizes; (void)n_in; (void)out_size; (void)ws_size;
  const float* x  = (const float*)d_in[0];
  const float* Wq = (const float*)d_in[1];
  const float* Wk = (const float*)d_in[2];
  const float* Wv = (const float*)d_in[3];
  const float* Wo = (const float*)d_in[4];
  const float* Pk = (const float*)d_in[5];
  const float* Pv = (const float*)d_in[6];

  ushort* wsu = (ushort*)d_ws;
  ushort* PkT     = wsu;                   // 8*256*4096
  ushort* PvT     = PkT + 8388608;
  ushort* WkQT    = PvT + 8388608;         // 8*128*128
  ushort* WvoT    = WkQT + 131072;
  ushort* MQ      = WvoT + 131072;         // 64*256*128
  ushort* vo_redT = MQ + 2097152;          // 64*128*256
  ushort* xT = (ushort*)d_out;             // 67 MB scratch; k2 overwrites d_out

  k0_weights<<<dim3(2, NG), dim3(512), 0, stream>>>(Wq, Wk, Wv, Wo, WkQT, WvoT);
  kt_xp<<<dim3(4096 + 2048), dim3(256), 0, stream>>>(x, Pk, Pv, xT, PkT, PvT);
  k1_mfma<<<dim3(256), dim3(256), 0, stream>>>(PkT, PvT, xT, WkQT, WvoT,
                                               MQ, vo_redT);
  k2_attn<<<dim3(512), dim3(512), 0, stream>>>(x, MQ, vo_redT, (float*)d_out);
}

// Round 18
// 229.599 us; speedup vs baseline: 1.0531x; 1.0531x over previous
//
#include <hip/hip_runtime.h>
#include <hip/hip_bf16.h>

#define NB 8
#define NG 8
#define NT 4096
#define NDIM 1024
#define NGD 128
#define NATT 128
#define NKL 256
#define FSCALE 0.08838834764831845f  // 1/sqrt(128)

typedef __bf16 bf16x8 __attribute__((ext_vector_type(8)));
typedef float f32x4 __attribute__((ext_vector_type(4)));
typedef ushort u16x8 __attribute__((ext_vector_type(8)));
typedef ushort u16x4 __attribute__((ext_vector_type(4)));

#define MFMA(a, b, c) __builtin_amdgcn_mfma_f32_16x16x32_bf16(a, b, c, 0, 0, 0)

__device__ __forceinline__ ushort f2bf(float f) {  // RNE
  union { float f; unsigned u; } v; v.f = f;
  unsigned r = v.u + 0x7FFFu + ((v.u >> 16) & 1u);
  return (ushort)(r >> 16);
}

__device__ __forceinline__ void gload16(const ushort* g, ushort* l) {
  __builtin_amdgcn_global_load_lds(
      (const __attribute__((address_space(1))) unsigned int*)g,
      (__attribute__((address_space(3))) unsigned int*)l, 16, 0, 0);
}

// ---------------------------------------------------------------------------
// K0: weight folding. FROZEN (R12-proven, ~8 us).
// ---------------------------------------------------------------------------
__global__ __launch_bounds__(512) void k0_weights(
    const float* __restrict__ Wq, const float* __restrict__ Wk,
    const float* __restrict__ Wv, const float* __restrict__ Wo,
    ushort* __restrict__ WkQT, ushort* __restrict__ WvoT) {
  const int sel = blockIdx.x;
  const int g = blockIdx.y;
  __shared__ float A2[128 * 136];
  __shared__ float B2[128 * 136];
  const int tid = threadIdx.x;

  if (sel == 0) {
#pragma unroll
    for (int u = 0; u < 8; ++u) {
      const int c = tid + 512 * u;
      const int row = c >> 5, c4 = (c & 31) * 4;
      *(float4*)&A2[row * 136 + c4] =
          *(const float4*)&Wo[(size_t)g * 16384 + row * 128 + c4];
      const float4 v = *(const float4*)&Wv[(size_t)g * 16384 + row * 128 + c4];
      B2[(c4 + 0) * 136 + row] = v.x;
      B2[(c4 + 1) * 136 + row] = v.y;
      B2[(c4 + 2) * 136 + row] = v.z;
      B2[(c4 + 3) * 136 + row] = v.w;
    }
  } else {
#pragma unroll
    for (int u = 0; u < 8; ++u) {
      const int c = tid + 512 * u;
      const int row = c >> 5, c4 = (c & 31) * 4;
      const float4 q = *(const float4*)&Wq[(size_t)g * 16384 + row * 128 + c4];
      A2[(c4 + 0) * 136 + row] = q.x;
      A2[(c4 + 1) * 136 + row] = q.y;
      A2[(c4 + 2) * 136 + row] = q.z;
      A2[(c4 + 3) * 136 + row] = q.w;
      const float4 k = *(const float4*)&Wk[(size_t)g * 16384 + row * 128 + c4];
      B2[(c4 + 0) * 136 + row] = k.x;
      B2[(c4 + 1) * 136 + row] = k.y;
      B2[(c4 + 2) * 136 + row] = k.z;
      B2[(c4 + 3) * 136 + row] = k.w;
    }
  }
  __syncthreads();

  const int mr = tid >> 4;
  const int mc = tid & 15;
  float acc[4][8];
#pragma unroll
  for (int i = 0; i < 4; ++i)
#pragma unroll
    for (int j = 0; j < 8; ++j) acc[i][j] = 0.f;

#pragma unroll 4
  for (int k = 0; k < 128; ++k) {
    const float4 a = *(const float4*)&A2[k * 136 + mr * 4];
    const float4 b0 = *(const float4*)&B2[k * 136 + mc * 8];
    const float4 b1 = *(const float4*)&B2[k * 136 + mc * 8 + 4];
    const float av[4] = {a.x, a.y, a.z, a.w};
    const float bv[8] = {b0.x, b0.y, b0.z, b0.w, b1.x, b1.y, b1.z, b1.w};
#pragma unroll
    for (int i = 0; i < 4; ++i)
#pragma unroll
      for (int j = 0; j < 8; ++j) acc[i][j] += av[i] * bv[j];
  }

  const float sc = sel ? FSCALE : 1.f;
  ushort* dst = (sel ? WkQT : WvoT) + (size_t)g * 16384;
#pragma unroll
  for (int i = 0; i < 4; ++i) {
    u16x8 pk;
#pragma unroll
    for (int j = 0; j < 8; ++j) pk[j] = f2bf(acc[i][j] * sc);
    *(u16x8*)&dst[(size_t)(mr * 4 + i) * 128 + mc * 8] = pk;
  }
}

// ---------------------------------------------------------------------------
// KT_XP: merged transpose kernel (one launch). FROZEN (R12-proven; at its
// HBM floor ~301 MB of traffic).
// ---------------------------------------------------------------------------
__global__ __launch_bounds__(256) void kt_xp(
    const float* __restrict__ x, const float* __restrict__ Pk,
    const float* __restrict__ Pv, ushort* __restrict__ xT,
    ushort* __restrict__ PkT, ushort* __restrict__ PvT) {
  __shared__ float buf[64 * 132];
  const int bid = blockIdx.x;
  const int tid = threadIdx.x;

  if (bid < 4096) {
    const int t0 = (bid & 63) * 64;
    const int bg = bid >> 6;
    const int b = bg >> 3, g = bg & 7;
#pragma unroll
    for (int u = 0; u < 8; ++u) {
      const int c = tid + 256 * u;
      const int row = c >> 5, c4 = (c & 31) * 4;
      *(float4*)&buf[row * 132 + c4] =
          *(const float4*)&x[((size_t)b * NT + t0 + row) * NDIM + g * 128 + c4];
    }
    __syncthreads();
    const int seg = tid & 7;
    const int d0 = tid >> 3;
#pragma unroll
    for (int u = 0; u < 4; ++u) {
      const int d = d0 + u * 32;
      u16x8 pk;
#pragma unroll
      for (int z = 0; z < 8; ++z) pk[z] = f2bf(buf[(seg * 8 + z) * 132 + d]);
      *(u16x8*)&xT[((size_t)bg * 128 + d) * NT + t0 + seg * 8] = pk;
    }
  } else {
    const int idx = bid - 4096;
    const float* P = (idx >> 10) ? Pv : Pk;
    ushort* PT = (idx >> 10) ? PvT : PkT;
    const int r_ = idx & 1023;
    const int t0 = (r_ & 63) * 64;
    const int klh = (r_ >> 6) & 1;
    const int g = (r_ >> 7) & 7;
#pragma unroll
    for (int u = 0; u < 8; ++u) {
      const int c = tid + 256 * u;
      const int row = c >> 5, c4 = (c & 31) * 4;
      *(float4*)&buf[row * 132 + c4] =
          *(const float4*)&P[((size_t)g * NT + t0 + row) * NKL + klh * 128 + c4];
    }
    __syncthreads();
    const int seg = tid & 7;
    const int k0_ = tid >> 3;
#pragma unroll
    for (int u = 0; u < 4; ++u) {
      const int kl = k0_ + u * 32;
      u16x8 pk;
#pragma unroll
      for (int z = 0; z < 8; ++z) pk[z] = f2bf(buf[(seg * 8 + z) * 132 + kl]);
      *(u16x8*)&PT[((size_t)g * NKL + klh * 128 + kl) * NT + t0 + seg * 8] = pk;
    }
  }
}

// ---------------------------------------------------------------------------
// K1: C1 = P^T@X (128kl x 128d, K=4096, BK=64, global_load_lds dbuf, XOR
// swizzle key row&7), epilogue C2 = C1@W. FROZEN (R12-proven).
// ---------------------------------------------------------------------------
__global__ __launch_bounds__(256, 2) void k1_mfma(
    const ushort* __restrict__ PkT, const ushort* __restrict__ PvT,
    const ushort* __restrict__ xT, const ushort* __restrict__ WkQT,
    const ushort* __restrict__ WvoT, ushort* __restrict__ MQ,
    ushort* __restrict__ vo_redT) {
  const int bid = blockIdx.x;
  const int work = (bid & 7) * 32 + (bid >> 3);  // cluster 8 bg per XCD
  const int bg = work >> 2;
  const int sel = (work >> 1) & 1;
  const int klt = work & 1;
  const int g = bg & 7;
  const ushort* PT = (sel ? PvT : PkT) + ((size_t)g * NKL + klt * 128) * NT;
  const ushort* Xb = xT + (size_t)bg * 128 * NT;

  __shared__ ushort lds[32768];  // 2 bufs x (A 128x64 + B 128x64); C reuse

  const int tid = threadIdx.x;
  const int w = tid >> 6, lane = tid & 63;
  const int l15 = lane & 15, l4 = lane >> 4;
  const int rh = (w & 1) * 64;
  const int ch = (w >> 1) * 64;
  const int srow = lane >> 3, sc = lane & 7;

  f32x4 acc[4][4];
  const f32x4 fz = {0.f, 0.f, 0.f, 0.f};
#pragma unroll
  for (int i = 0; i < 4; ++i)
#pragma unroll
    for (int j = 0; j < 4; ++j) acc[i][j] = fz;

#define K1_STAGE(buf, s)                                                      \
  {                                                                           \
    const int t0_ = (s) * 64;                                                 \
    ushort* Ab_ = &lds[(buf) * 16384];                                        \
    ushort* Bb_ = &lds[(buf) * 16384 + 8192];                                 \
    _Pragma("unroll") for (int u = 0; u < 4; ++u) {                           \
      const int row_ = w * 32 + u * 8 + srow;                                 \
      const size_t off_ = (size_t)row_ * NT + t0_ + ((sc ^ (row_ & 7)) << 3); \
      gload16(PT + off_, Ab_ + (w * 32 + u * 8) * 64);                        \
      gload16(Xb + off_, Bb_ + (w * 32 + u * 8) * 64);                        \
    }                                                                         \
  }

#define K1_COMPUTE(buf)                                                       \
  {                                                                           \
    const ushort* Ab_ = &lds[(buf) * 16384];                                  \
    const ushort* Bb_ = &lds[(buf) * 16384 + 8192];                           \
    _Pragma("unroll") for (int h = 0; h < 2; ++h) {                           \
      bf16x8 af_[4], bf_[4];                                                  \
      _Pragma("unroll") for (int i = 0; i < 4; ++i) {                         \
        const int row_ = rh + i * 16 + l15;                                   \
        af_[i] = *(const bf16x8*)&Ab_[row_ * 64 +                             \
                                      (((h * 4 + l4) ^ (row_ & 7)) << 3)];    \
      }                                                                       \
      _Pragma("unroll") for (int j = 0; j < 4; ++j) {                         \
        const int row_ = ch + j * 16 + l15;                                   \
        bf_[j] = *(const bf16x8*)&Bb_[row_ * 64 +                             \
                                      (((h * 4 + l4) ^ (row_ & 7)) << 3)];    \
      }                                                                       \
      _Pragma("unroll") for (int i = 0; i < 4; ++i)                           \
        _Pragma("unroll") for (int j = 0; j < 4; ++j)                         \
          acc[i][j] = MFMA(af_[i], bf_[j], acc[i][j]);                        \
    }                                                                         \
  }

  K1_STAGE(0, 0);
  __syncthreads();
  int buf = 0;
#pragma unroll 1
  for (int s = 0; s < 64; ++s) {
    if (s + 1 < 64) K1_STAGE(buf ^ 1, s + 1);
    K1_COMPUTE(buf);
    __syncthreads();
    buf ^= 1;
  }

  ushort* C = lds;
#pragma unroll
  for (int i = 0; i < 4; ++i)
#pragma unroll
    for (int j = 0; j < 4; ++j)
#pragma unroll
      for (int r = 0; r < 4; ++r)
        C[(rh + i * 16 + l4 * 4 + r) * 136 + ch + j * 16 + l15] =
            f2bf(acc[i][j][r]);
  __syncthreads();

  const ushort* WT = (sel ? WvoT : WkQT) + (size_t)g * 16384;
  f32x4 o[4][4];
#pragma unroll
  for (int i = 0; i < 4; ++i)
#pragma unroll
    for (int j = 0; j < 4; ++j) o[i][j] = fz;
#pragma unroll
  for (int ks = 0; ks < 4; ++ks) {
    bf16x8 af[4], bfr[4];
#pragma unroll
    for (int i = 0; i < 4; ++i)
      af[i] = *(const bf16x8*)&C[(rh + i * 16 + l15) * 136 + ks * 32 + l4 * 8];
#pragma unroll
    for (int j = 0; j < 4; ++j)
      bfr[j] = *(const bf16x8*)&WT[(size_t)(ch + j * 16 + l15) * 128 + ks * 32 + l4 * 8];
#pragma unroll
    for (int i = 0; i < 4; ++i)
#pragma unroll
      for (int j = 0; j < 4; ++j) o[i][j] = MFMA(af[i], bfr[j], o[i][j]);
  }

  if (sel == 0) {
#pragma unroll
    for (int i = 0; i < 4; ++i)
#pragma unroll
      for (int j = 0; j < 4; ++j)
#pragma unroll
        for (int r = 0; r < 4; ++r)
          MQ[((size_t)bg * NKL + klt * 128 + rh + i * 16 + l4 * 4 + r) * 128 +
             ch + j * 16 + l15] = f2bf(o[i][j][r]);
  } else {
#pragma unroll
    for (int i = 0; i < 4; ++i)
#pragma unroll
      for (int j = 0; j < 4; ++j) {
        u16x4 pk;
#pragma unroll
        for (int r = 0; r < 4; ++r) pk[r] = f2bf(o[i][j][r]);
        *(u16x4*)&vo_redT[((size_t)bg * 128 + ch + j * 16 + l15) * NKL +
                          klt * 128 + rh + i * 16 + l4 * 4] = pk;
      }
  }
}

// ---------------------------------------------------------------------------
// K2: R14/R16 configuration, FINAL. The verified optimum of this structure
// family (105 us, FETCH 73.8 MB, WRITE 131 MB = exactly `out`, reproduced
// twice). Measured dead ends around it: 6 register restructures spilled
// (R5-R10, R13); no-mq-LDS thrashes L2 (R8/R15); barrier-halving costs more
// VALU than it saves (R17: 105->111 us). Register layout s[8]+oa[4]+xr[8]
// with cross-wave softmax via small LDS; 1-D XCD-clustered grid.
// ---------------------------------------------------------------------------
__global__ __launch_bounds__(512, 2) void k2_attn(
    const float* __restrict__ x, const ushort* __restrict__ MQ,
    const ushort* __restrict__ vo_redT, float* __restrict__ out) {
  const int id = blockIdx.x;
  const int bg = id & 63;  // same-bg blocks co-locate on XCD bg%8
  const int tc = id >> 6;  // 0..7, 512 t-rows each
  const int b = bg >> 3, g = bg & 7;

  __shared__ ushort mq[256 * 136];   // 69632 B
  __shared__ ushort att[64 * 264];   // 33792 B
  __shared__ float redm[2][64];
  __shared__ float reds[2][64];

  const int tid = threadIdx.x;
  const int w = tid >> 6, lane = tid & 63;
  const int l15 = lane & 15, l4 = lane >> 4;
  const int tw = w >> 1, half = w & 1;
  const f32x4 fz = {0.f, 0.f, 0.f, 0.f};

  {  // stage MQ[bg] -> LDS (padded rows)
    const ushort* src = MQ + (size_t)bg * NKL * 128;
#pragma unroll
    for (int u = 0; u < 8; ++u) {
      const int c = tid + 512 * u;
      const int r = c >> 4, c8 = (c & 15) * 8;
      *(u16x8*)&mq[r * 136 + c8] = *(const u16x8*)&src[r * 128 + c8];
    }
  }

  const float* xb = x + ((size_t)b * NT + tc * 512) * NDIM + g * 128;
  const ushort* vo = vo_redT + ((size_t)bg * 128 + half * 64) * NKL;

  float4 xr[8];  // x fragments for current step (prefetched)
#pragma unroll
  for (int ks = 0; ks < 4; ++ks) {
    const float* p = xb + (size_t)(tw * 16 + l15) * NDIM + ks * 32 + l4 * 8;
    xr[ks * 2] = *(const float4*)p;
    xr[ks * 2 + 1] = *(const float4*)(p + 4);
  }
  __syncthreads();

#pragma unroll 1
  for (int st = 0; st < 8; ++st) {
    // convert current x frags to bf16
    bf16x8 a[4];
#pragma unroll
    for (int ks = 0; ks < 4; ++ks) {
      bf16x8 t;
      t[0] = (__bf16)xr[ks * 2].x; t[1] = (__bf16)xr[ks * 2].y;
      t[2] = (__bf16)xr[ks * 2].z; t[3] = (__bf16)xr[ks * 2].w;
      t[4] = (__bf16)xr[ks * 2 + 1].x; t[5] = (__bf16)xr[ks * 2 + 1].y;
      t[6] = (__bf16)xr[ks * 2 + 1].z; t[7] = (__bf16)xr[ks * 2 + 1].w;
      a[ks] = t;
    }
    // prefetch next step's x frags (hides HBM latency under softmax+PV)
    if (st + 1 < 8) {
      const float* pn = xb + (size_t)((st + 1) * 64 + tw * 16 + l15) * NDIM;
#pragma unroll
      for (int ks = 0; ks < 4; ++ks) {
        xr[ks * 2] = *(const float4*)(pn + ks * 32 + l4 * 8);
        xr[ks * 2 + 1] = *(const float4*)(pn + ks * 32 + l4 * 8 + 4);
      }
    }
    // S = x @ MQ^T  (wave: t-tile tw, kl-half `half`)
    f32x4 s[8];
#pragma unroll
    for (int n = 0; n < 8; ++n) s[n] = fz;
#pragma unroll
    for (int n = 0; n < 8; ++n) {
      const int row = (half * 8 + n) * 16 + l15;
#pragma unroll
      for (int ks = 0; ks < 4; ++ks) {
        const bf16x8 bv = *(const bf16x8*)&mq[row * 136 + ks * 32 + l4 * 8];
        s[n] = MFMA(a[ks], bv, s[n]);
      }
    }
    // softmax: rows tw*16 + l4*4 + r
    const int rowbase = tw * 16 + l4 * 4;
    float inv[4];
    {
      float mx[4];
#pragma unroll
      for (int r = 0; r < 4; ++r) {
        float m = s[0][r];
#pragma unroll
        for (int n = 1; n < 8; ++n) m = fmaxf(m, s[n][r]);
#pragma unroll
        for (int off = 1; off < 16; off <<= 1) m = fmaxf(m, __shfl_xor(m, off, 64));
        mx[r] = m;
      }
      if (l15 == 0) {
#pragma unroll
        for (int r = 0; r < 4; ++r) redm[half][rowbase + r] = mx[r];
      }
      __syncthreads();  // sync1
      float sm[4];
#pragma unroll
      for (int r = 0; r < 4; ++r) {
        const float mg = fmaxf(mx[r], redm[half ^ 1][rowbase + r]);
        float acc = 0.f;
#pragma unroll
        for (int n = 0; n < 8; ++n) {
          const float p = __expf(s[n][r] - mg);
          acc += p;
          att[(rowbase + r) * 264 + (half * 8 + n) * 16 + l15] = f2bf(p);
        }
#pragma unroll
        for (int off = 1; off < 16; off <<= 1) acc += __shfl_xor(acc, off, 64);
        sm[r] = acc;
      }
      if (l15 == 0) {
#pragma unroll
        for (int r = 0; r < 4; ++r) reds[half][rowbase + r] = sm[r];
      }
      __syncthreads();  // sync2
#pragma unroll
      for (int r = 0; r < 4; ++r)
        inv[r] = 1.f / (sm[r] + reds[half ^ 1][rowbase + r]);
    }
    // PV: O = att @ vo_redT  (wave: t-tile tw, d-half `half`)
    f32x4 oa[4];
#pragma unroll
    for (int j = 0; j < 4; ++j) oa[j] = fz;
#pragma unroll
    for (int ks = 0; ks < 8; ++ks) {
      const bf16x8 av = *(const bf16x8*)&att[(tw * 16 + l15) * 264 + ks * 32 + l4 * 8];
#pragma unroll
      for (int j = 0; j < 4; ++j) {
        const bf16x8 bv = *(const bf16x8*)&vo[(size_t)(j * 16 + l15) * NKL + ks * 32 + l4 * 8];
        oa[j] = MFMA(av, bv, oa[j]);
      }
    }
    // store with 1/sum
    float* ob = out + ((size_t)b * NT + tc * 512 + st * 64 + tw * 16) * NDIM +
                g * 128 + half * 64;
#pragma unroll
    for (int j = 0; j < 4; ++j)
#pragma unroll
      for (int r = 0; r < 4; ++r)
        ob[(size_t)(l4 * 4 + r) * NDIM + j * 16 + l15] = oa[j][r] * inv[r];
  }
}

// ---------------------------------------------------------------------------
extern "C" void kernel_launch(void* const* d_in, const int* in_sizes, int n_in,
                              void* d_out, int out_size, void* d_ws, size_t ws_size,
                              hipStream_t stream) {
  (void)in_sizes; (void)n_in; (void)out_size; (void)ws_size;
  const float* x  = (const float*)d_in[0];
  const float* Wq = (const float*)d_in[1];
  const float* Wk = (const float*)d_in[2];
  const float* Wv = (const float*)d_in[3];
  const float* Wo = (const float*)d_in[4];
  const float* Pk = (const float*)d_in[5];
  const float* Pv = (const float*)d_in[6];

  ushort* wsu = (ushort*)d_ws;
  ushort* PkT     = wsu;                   // 8*256*4096
  ushort* PvT     = PkT + 8388608;
  ushort* WkQT    = PvT + 8388608;         // 8*128*128
  ushort* WvoT    = WkQT + 131072;
  ushort* MQ      = WvoT + 131072;         // 64*256*128
  ushort* vo_redT = MQ + 2097152;          // 64*128*256
  ushort* xT = (ushort*)d_out;             // 67 MB scratch; k2 overwrites d_out

  k0_weights<<<dim3(2, NG), dim3(512), 0, stream>>>(Wq, Wk, Wv, Wo, WkQT, WvoT);
  kt_xp<<<dim3(4096 + 2048), dim3(256), 0, stream>>>(x, Pk, Pv, xT, PkT, PvT);
  k1_mfma<<<dim3(256), dim3(256), 0, stream>>>(PkT, PvT, xT, WkQT, WvoT,
                                               MQ, vo_redT);
  k2_attn<<<dim3(512), dim3(512), 0, stream>>>(x, MQ, vo_redT, (float*)d_out);
}